// Round 9
// baseline (165.104 us; speedup 1.0000x reference)
//
#include <hip/hip_runtime.h>

// B=16, T=1024, N=1024, D=256, WIN=64
// outputs (flat): R (B,T,2D) = [A@V, Q]   : 8388608 f32
//                 alignments (B,N,T) = A^T: 16777216 f32
//                 max_att (B,T)           : 16384 f32
//
// v15 = v14b (158.7us; nt stores on all outputs) + ONE mechanism:
// single-cohort residency.
//   Accounting: grid = 1264 blocks but LDS 38.4KB -> only 4 blocks/CU =
//   1024 slots. The 240 zero-role blocks (dispatched first) each hold a
//   38.4KB LDS allocation + slot until their 256KB of nt stores ack
//   (s_waitcnt vmcnt(0) before s_endpgm) -> 240 attn blocks pushed into a
//   second cohort, extending the span ~10us.
//   Fix: LDS < 32KB -> 5 blocks/CU -> 1280 slots >= 1264 blocks, whole grid
//   resident at once; the 63MB zero drain fully overlaps attn compute.
//  - K staged in THREE slices (96,96,64 dims) into ks[64][100].
//    100%32==4: same empirically-conflict-free b128 stride class as
//    132/260 (v8/v10 measured ~0 conflicts). LDS 25.6+4.4=30KB.
//  - __launch_bounds__(256,5) (VGPR cap 102; v11 measured 64).
//  - everything else v14b verbatim: TBLK=16, barrier-protected strip
//    transpose, nt stores, zeros-first roles.

#define BB 16
#define TT 1024
#define NN 1024
#define DD 256
#define WIN 64
#define TBLK 16          // queries per attn block
#define NT 256           // 4 waves, 4 queries each
#define NZ 240           // zero-streaming blocks (16 batches x 15)

#define R_ELEMS   (16u*1024u*512u)        // 8388608
#define ALN_ELEMS (16u*1024u*1024u)       // 16777216

#define LSTR 100         // LDS row stride (dwords); 100%32==4 -> conflict-free b128

typedef float f32x4 __attribute__((ext_vector_type(4)));

__device__ __forceinline__ void nts4(void* p, float4 v) {
    f32x4 nv;
    nv.x = v.x; nv.y = v.y; nv.z = v.z; nv.w = v.w;
    __builtin_nontemporal_store(nv, (f32x4*)p);
}

__global__ __launch_bounds__(NT, 5) void attn_v15(
    const float* __restrict__ Q, const float* __restrict__ K,
    const float* __restrict__ V, const int* __restrict__ prev_in,
    float* __restrict__ out)
{
    __shared__ float ks[WIN * LSTR];        // 25600 B: K slice (64 rows x <=96d)
    __shared__ float p_lds[TBLK][WIN + 4];  //  4352 B: probabilities [t][j]

    float* Rout   = out;
    float* aligns = out + R_ELEMS;
    float* maxatt = out + R_ELEMS + ALN_ELEMS;

    const int tid = threadIdx.x;

    // ================= role 1: zero-streaming blocks =================
    if (blockIdx.x < NZ) {
        const int zb    = blockIdx.x;
        const int b     = zb / 15;          // 15 blocks per batch
        const int chunk = zb % 15;          // 64 rows each
        const int prev  = prev_in[b];
        float* zbase = aligns + (size_t)b * NN * TT;
        const float4 z = make_float4(0.f, 0.f, 0.f, 0.f);
        #pragma unroll 8
        for (int r = 0; r < 64; ++r) {
            int idx = chunk * 64 + r;          // 0..959 among non-window rows
            int n   = idx < prev ? idx : idx + WIN;
            nts4(zbase + (size_t)n * 1024 + tid * 4, z);  // nt: no L2 allocation
        }
        return;                                // stores drain under attn compute
    }

    // ================= role 2: attention blocks =================
    const int aid  = blockIdx.x - NZ;
    const int lane = tid & 63;
    const int w    = __builtin_amdgcn_readfirstlane(tid >> 6);  // wave 0..3
    const int b    = aid >> 6;              // 64 blocks per batch
    const int t0   = (aid & 63) * TBLK;
    const int prev = prev_in[b];

    const float* qb = Q + ((size_t)b * TT + t0 + 4 * w) * DD;   // wave-uniform base

    // ---- hoisted Q copy (nt store: R never re-read) ----
    #pragma unroll
    for (int t = 0; t < 4; ++t) {
        float4 qv = ((const float4*)(qb + t * DD))[lane];
        float* Rrow = Rout + ((size_t)b * TT + t0 + 4 * w + t) * (2 * DD);
        nts4(Rrow + DD + lane * 4, qv);
    }

    // ============ QK^T over three dim-slices: 96, 96, 64 ============
    float acc[4] = {0.f, 0.f, 0.f, 0.f};
    #pragma unroll
    for (int s = 0; s < 3; ++s) {
        const int d0  = s * 96;                  // 0, 96, 192
        const int nd4 = (s < 2) ? 24 : 16;       // float4 cols this slice
        if (s) __syncthreads();                  // previous slice's readers done
        const float4* Ksrc = (const float4*)(K + ((size_t)b * NN + prev) * DD + d0);
        const int nchunks = WIN * nd4;           // 1536 or 1024
        for (int k = 0; k < 6; ++k) {            // 6 or 4 iterations used
            int idx = tid + k * NT;
            if (idx < nchunks) {
                int r = idx / nd4, c = idx % nd4;
                float4 v = Ksrc[(size_t)r * 64 + c];
                *(float4*)&ks[r * LSTR + c * 4] = v;
            }
        }
        __syncthreads();

        const float* qh = qb + d0;
        #pragma unroll 8
        for (int d4 = 0; d4 < nd4; ++d4) {
            float4 kk = *(const float4*)&ks[lane * LSTR + d4 * 4];  // conflict-free b128
            #pragma unroll
            for (int t = 0; t < 4; ++t) {
                float4 q = ((const float4*)(qh + t * DD))[d4];      // wave-uniform
                acc[t] = fmaf(q.x, kk.x, fmaf(q.y, kk.y, fmaf(q.z, kk.z, fmaf(q.w, kk.w, acc[t]))));
            }
        }
    }

    // ================= softmax + argmax (wave-local), p -> LDS ===========
    #pragma unroll
    for (int t = 0; t < 4; ++t) {
        float v = acc[t] * 0.0625f;         // 1/sqrt(256)

        float m = v;
        #pragma unroll
        for (int off = 32; off; off >>= 1) m = fmaxf(m, __shfl_xor(m, off));

        float e = expf(v - m);
        float s = e;
        #pragma unroll
        for (int off = 32; off; off >>= 1) s += __shfl_xor(s, off);

        p_lds[4 * w + t][lane] = e / s;

        float av = v; int ai = lane;
        #pragma unroll
        for (int off = 32; off; off >>= 1) {
            float ov = __shfl_xor(av, off);
            int   oi = __shfl_xor(ai, off);
            if (ov > av || (ov == av && oi < ai)) { av = ov; ai = oi; }
        }
        if (lane == 0)
            __builtin_nontemporal_store((float)(prev + ai),
                                        &maxatt[(size_t)b * TT + t0 + 4 * w + t]);
    }
    __syncthreads();                        // all 16 p rows visible

    // ===== window-row alignment strip: 64 rows x 16 floats (64B lines) ====
    // Zero blocks never touch these rows -> written exactly once.
    {
        const int j = tid >> 2, cg = tid & 3;
        float4 v;
        v.x = p_lds[cg * 4 + 0][j];
        v.y = p_lds[cg * 4 + 1][j];
        v.z = p_lds[cg * 4 + 2][j];
        v.w = p_lds[cg * 4 + 3][j];
        nts4(aligns + ((size_t)b * NN + prev + j) * TT + t0 + cg * 4, v);
    }

    // ================= PV direct from global (L2-hot V) ==================
    // lane = d-chunk (64 x float4 = 256 d); reads own wave's p rows.
    {
        const float4* V4 = (const float4*)(V + ((size_t)b * NN + prev) * DD);
        float4 o[4];
        #pragma unroll
        for (int t = 0; t < 4; ++t) o[t] = make_float4(0.f, 0.f, 0.f, 0.f);

        #pragma unroll 4
        for (int j4 = 0; j4 < WIN / 4; ++j4) {
            float4 p0 = *(const float4*)&p_lds[4 * w + 0][j4 * 4];  // uniform bcast
            float4 p1 = *(const float4*)&p_lds[4 * w + 1][j4 * 4];
            float4 p2 = *(const float4*)&p_lds[4 * w + 2][j4 * 4];
            float4 p3 = *(const float4*)&p_lds[4 * w + 3][j4 * 4];
            float4 v0 = V4[(size_t)(j4 * 4 + 0) * 64 + lane];
            float4 v1 = V4[(size_t)(j4 * 4 + 1) * 64 + lane];
            float4 v2 = V4[(size_t)(j4 * 4 + 2) * 64 + lane];
            float4 v3 = V4[(size_t)(j4 * 4 + 3) * 64 + lane];
            #define ACC4(o_, p_) \
                o_.x = fmaf(p_.x, v0.x, fmaf(p_.y, v1.x, fmaf(p_.z, v2.x, fmaf(p_.w, v3.x, o_.x)))); \
                o_.y = fmaf(p_.x, v0.y, fmaf(p_.y, v1.y, fmaf(p_.z, v2.y, fmaf(p_.w, v3.y, o_.y)))); \
                o_.z = fmaf(p_.x, v0.z, fmaf(p_.y, v1.z, fmaf(p_.z, v2.z, fmaf(p_.w, v3.z, o_.z)))); \
                o_.w = fmaf(p_.x, v0.w, fmaf(p_.y, v1.w, fmaf(p_.z, v2.w, fmaf(p_.w, v3.w, o_.w))));
            ACC4(o[0], p0) ACC4(o[1], p1) ACC4(o[2], p2) ACC4(o[3], p3)
            #undef ACC4
        }

        #pragma unroll
        for (int t = 0; t < 4; ++t) {
            float* Rrow = Rout + ((size_t)b * TT + t0 + 4 * w + t) * (2 * DD);
            nts4(Rrow + lane * 4, o[t]);    // A@V (Q half already written)
        }
    }
}

extern "C" void kernel_launch(void* const* d_in, const int* in_sizes, int n_in,
                              void* d_out, int out_size, void* d_ws, size_t ws_size,
                              hipStream_t stream) {
    const float* Q = (const float*)d_in[0];
    const float* K = (const float*)d_in[1];
    const float* V = (const float*)d_in[2];
    const int* prev = (const int*)d_in[3];
    float* out = (float*)d_out;

    // single launch: 240 zero-streaming blocks first, then 1024 attn blocks;
    // whole grid (1264 blocks) resident in one cohort at 5 blocks/CU.
    attn_v15<<<NZ + BB * TT / TBLK, NT, 0, stream>>>(Q, K, V, prev, out);
}